// Round 1
// 747.883 us; speedup vs baseline: 1.1267x; 1.1267x over previous
//
#include <hip/hip_runtime.h>
#include <hip/hip_bf16.h>

typedef __bf16 bf16;
typedef float f32x4 __attribute__((ext_vector_type(4)));
typedef bf16 bf16x8 __attribute__((ext_vector_type(8)));
typedef bf16 bf16x4 __attribute__((ext_vector_type(4)));

#define E_TOT 400000
#define TE 64          // edges per block
#define SROW 264       // LDS activation row stride (bf16 elems), 256+8 pad

// ---------------------------------------------------------------------------
// exact GELU: 0.5x(1+erf(x/sqrt(2))), erf via Abramowitz-Stegun 7.1.26
// (|err| <= 1.5e-7), ~15 VALU ops vs ~30+ for libm erff.
// ---------------------------------------------------------------------------
__device__ __forceinline__ float gelu_exact(float x){
  float z = fabsf(x) * 0.70710678118654752f;
  float t = 1.0f / __builtin_fmaf(0.3275911f, z, 1.0f);
  float p = __builtin_fmaf(1.061405429f, t, -1.453152027f);
  p = __builtin_fmaf(p, t, 1.421413741f);
  p = __builtin_fmaf(p, t, -0.284496736f);
  p = __builtin_fmaf(p, t, 0.254829592f);
  p = p * t;
  float ex = __expf(-z * z);
  float er = __builtin_fmaf(-p, ex, 1.0f);
  er = copysignf(er, x);
  return 0.5f * x * (1.0f + er);
}

// ---------------------------------------------------------------------------
// G = feature_emb @ feature_emb.T  (64x64, fp32 in / fp32 out)
// ---------------------------------------------------------------------------
__global__ void compute_g(const float* __restrict__ fe, float* __restrict__ Gm){
  const int a = blockIdx.x, f = threadIdx.x;
  const float4* ra = (const float4*)(fe + a * 256);
  const float4* rf = (const float4*)(fe + f * 256);
  float s = 0.f;
  for (int h = 0; h < 64; ++h){
    float4 x = ra[h];
    float4 y = rf[h];
    s += x.x * y.x + x.y * y.y + x.z * y.z + x.w * y.w;
  }
  Gm[a * 64 + f] = s;
}

// ---------------------------------------------------------------------------
// Pre-swizzle fp32 weight W [Kd][Md] (row-major, input-dim x output-dim) into
// bf16 MFMA A-operand fragments: frag for tile t=(kt*Mtiles+mtg), lane L,
// elem j holds W[kt*32 + (L>>4)*8 + j][mtg*16 + (L&15)].
// ---------------------------------------------------------------------------
__global__ void swizzle_w(const float* __restrict__ src, bf16* __restrict__ dst,
                          int Kd, int Md){
  const int t = blockIdx.x;
  const int L = threadIdx.x;            // 64
  const int Mtiles = Md >> 4;
  const int kt = t / Mtiles, mtg = t % Mtiles;
  const int k0 = kt * 32 + (L >> 4) * 8;
  const int m  = mtg * 16 + (L & 15);
  bf16x8 v;
  #pragma unroll
  for (int j = 0; j < 8; ++j) v[j] = (bf16)src[(k0 + j) * Md + m];
  *(bf16x8*)&dst[((size_t)t * 64 + L) * 8] = v;
}

// ---------------------------------------------------------------------------
// Per-wave GEMM: OUTtile[m][e] += W^T[m][k] * ACT[e][k]
//   A operand = pre-swizzled bf16 weights (global, dwordx4 frags)
//   B operand = LDS activations, row-major [e][k] -> ds_read_b128
//   wave w owns output m-stripe [w*MT*16, (w+1)*MT*16)
// ---------------------------------------------------------------------------
template<int KT, int MT, int MTOT>
__device__ __forceinline__ void mfma_gemm(const bf16* __restrict__ Wz,
                                          const bf16* __restrict__ src,
                                          int w, int lane, f32x4 (&acc)[MT][4])
{
  const int l16 = lane & 15, quad = lane >> 4;
  #pragma unroll
  for (int mt = 0; mt < MT; ++mt)
    #pragma unroll
    for (int et = 0; et < 4; ++et) acc[mt][et] = f32x4{0.f, 0.f, 0.f, 0.f};
  #pragma unroll
  for (int kt = 0; kt < KT; ++kt){
    bf16x8 b[4];
    #pragma unroll
    for (int et = 0; et < 4; ++et)
      b[et] = *(const bf16x8*)&src[(et * 16 + l16) * SROW + kt * 32 + quad * 8];
    #pragma unroll
    for (int mt = 0; mt < MT; ++mt){
      const bf16x8 a = *(const bf16x8*)&Wz[(size_t)((kt * MTOT + (w * MT + mt)) * 64 + lane) * 8];
      #pragma unroll
      for (int et = 0; et < 4; ++et)
        acc[mt][et] = __builtin_amdgcn_mfma_f32_16x16x32_bf16(a, b[et], acc[mt][et], 0, 0, 0);
    }
  }
}

// ---------------------------------------------------------------------------
// Fused main kernel: 64 edges per block, 256 threads (4 waves).
// fp32 global I/O; bf16 LDS activations; fp32 MFMA accumulate.
//
// SINGLE LDS activation buffer: every GEMM's full output is held in acc[][]
// registers before write-back, so the classic RAW hazard is resolved with a
// barrier between "all waves finished k-loop reads" and "epilogue writes the
// same buffer".  LDS/block 71680 -> ~37.6 KB => 4 blocks/CU (was 2), i.e.
// 16 waves/CU.  Costs 3 extra __syncthreads (7 total), amortized by the
// gelu-heavy epilogues and cross-block overlap.
// ---------------------------------------------------------------------------
__global__ __launch_bounds__(256, 4) void fused_attr_net(
    const float* __restrict__ km,        // [100000,64]
    const int*   __restrict__ obs_idx,   // [E]
    const int*   __restrict__ omi_idx,   // [E]
    const int*   __restrict__ ai_idx,    // [E]
    const float* __restrict__ obs_embs,  // [100000,256]
    const float* __restrict__ b1g, const float* __restrict__ b2g,
    const float* __restrict__ rrbg, const float* __restrict__ rcbg,
    const float* __restrict__ Gm,        // [64,64] fp32
    const bf16* __restrict__ W1s, const bf16* __restrict__ W2s,
    const bf16* __restrict__ RRs, const bf16* __restrict__ RCs,
    float* __restrict__ out)
{
  __shared__ __align__(16) bf16 S_[TE * SROW];   // 33792 B, single buffer
  __shared__ int ai_s[TE];
  __shared__ int oi_s[TE];
  __shared__ __align__(16) float bias1[256];
  __shared__ __align__(16) float bias2[64];
  __shared__ __align__(16) float biasrr[256];
  __shared__ __align__(16) float biasrc[256];

  const int tid  = threadIdx.x;
  const int e0   = blockIdx.x * TE;
  const int lane = tid & 63;
  const int w    = tid >> 6;
  const int l16  = lane & 15;
  const int quad = lane >> 4;

  bias1[tid]  = b1g[tid];
  biasrr[tid] = rrbg[tid];
  biasrc[tid] = rcbg[tid];
  if (tid < TE){
    bias2[tid] = b2g[tid];
    ai_s[tid]  = ai_idx[e0 + tid];
    oi_s[tid]  = obs_idx[e0 + tid];
  }

  // ---- stage 0: SM = softmax(known_mask[omi] * (1-eye)[ai]) -> S_[e][0..63]
  {
    const int e = tid >> 2, part = tid & 3;      // 4 threads x 16 feats per edge
    const int omi = omi_idx[e0 + e];
    const int ai  = ai_idx[e0 + e];
    const float4* kr = (const float4*)(km + omi * 64 + part * 16);
    float s[16]; float cnt = 0.f;
    #pragma unroll
    for (int q = 0; q < 4; ++q){
      const float4 v4 = kr[q];
      const float vv[4] = {v4.x, v4.y, v4.z, v4.w};
      #pragma unroll
      for (int j = 0; j < 4; ++j){
        const int f = part * 16 + q * 4 + j;
        const float v = (f == ai) ? 0.f : vv[j];
        s[q * 4 + j] = v; cnt += v;
      }
    }
    cnt += __shfl_xor(cnt, 1);
    cnt += __shfl_xor(cnt, 2);
    // s in {0,1}: sum(exp) = cnt*e + (64-cnt)
    const float denom = __builtin_fmaf(cnt, 1.7182818284590452f, 64.0f);
    const float p0 = 1.0f / denom;
    const float p1 = 2.7182818284590452f * p0;
    bf16x8 o0, o1;
    #pragma unroll
    for (int j = 0; j < 8; ++j) o0[j] = (bf16)((s[j]     > 0.5f) ? p1 : p0);
    #pragma unroll
    for (int j = 0; j < 8; ++j) o1[j] = (bf16)((s[8 + j] > 0.5f) ? p1 : p0);
    *(bf16x8*)&S_[e * SROW + part * 16]     = o0;
    *(bf16x8*)&S_[e * SROW + part * 16 + 8] = o1;
  }
  __syncthreads();

  f32x4 acc[4][4];

  // ---- GEMM1: H1 = gelu(SM @ W1 + b1)  [64e x 256] -> S_
  mfma_gemm<2, 4, 16>(W1s, S_, w, lane, acc);
  __syncthreads();                      // all waves done reading SM
  #pragma unroll
  for (int mt = 0; mt < 4; ++mt){
    const int mbase = (w * 4 + mt) * 16 + quad * 4;
    const float4 bb = *(const float4*)&bias1[mbase];
    #pragma unroll
    for (int et = 0; et < 4; ++et){
      const int e = et * 16 + l16;
      bf16x4 o;
      o[0] = (bf16)gelu_exact(acc[mt][et][0] + bb.x);
      o[1] = (bf16)gelu_exact(acc[mt][et][1] + bb.y);
      o[2] = (bf16)gelu_exact(acc[mt][et][2] + bb.z);
      o[3] = (bf16)gelu_exact(acc[mt][et][3] + bb.w);
      *(bf16x4*)&S_[e * SROW + mbase] = o;
    }
  }
  __syncthreads();

  // ---- GEMM2: R = gelu(H1 @ W2 + b2) * G[ai]  [64e x 64] -> S_
  {
    f32x4 acc2[1][4];
    mfma_gemm<8, 1, 4>(W2s, S_, w, lane, acc2);
    __syncthreads();                    // all waves done reading H1
    const int mbase = w * 16 + quad * 4;
    const float4 bb = *(const float4*)&bias2[mbase];
    #pragma unroll
    for (int et = 0; et < 4; ++et){
      const int e = et * 16 + l16;
      const float4 g = *(const float4*)&Gm[ai_s[e] * 64 + mbase];
      bf16x4 o;
      o[0] = (bf16)(gelu_exact(acc2[0][et][0] + bb.x) * g.x);
      o[1] = (bf16)(gelu_exact(acc2[0][et][1] + bb.y) * g.y);
      o[2] = (bf16)(gelu_exact(acc2[0][et][2] + bb.z) * g.z);
      o[3] = (bf16)(gelu_exact(acc2[0][et][3] + bb.w) * g.w);
      *(bf16x4*)&S_[e * SROW + mbase] = o;
    }
  }
  __syncthreads();

  // ---- GEMM3: P = gelu(R @ rrW + rrb) * obs_embs[oi]  [64e x 256] -> S_
  mfma_gemm<2, 4, 16>(RRs, S_, w, lane, acc);
  __syncthreads();                      // all waves done reading R
  #pragma unroll
  for (int mt = 0; mt < 4; ++mt){
    const int mbase = (w * 4 + mt) * 16 + quad * 4;
    const float4 bb = *(const float4*)&biasrr[mbase];
    #pragma unroll
    for (int et = 0; et < 4; ++et){
      const int e = et * 16 + l16;
      const float4 oh = *(const float4*)&obs_embs[(size_t)oi_s[e] * 256 + mbase];
      bf16x4 o;
      o[0] = (bf16)(gelu_exact(acc[mt][et][0] + bb.x) * oh.x);
      o[1] = (bf16)(gelu_exact(acc[mt][et][1] + bb.y) * oh.y);
      o[2] = (bf16)(gelu_exact(acc[mt][et][2] + bb.z) * oh.z);
      o[3] = (bf16)(gelu_exact(acc[mt][et][3] + bb.w) * oh.w);
      *(bf16x4*)&S_[e * SROW + mbase] = o;
    }
  }
  __syncthreads();

  // ---- GEMM4: OUT = gelu(P @ rcW + rcb) -> direct fp32 global store
  mfma_gemm<8, 4, 16>(RCs, S_, w, lane, acc);
  #pragma unroll
  for (int mt = 0; mt < 4; ++mt){
    const int mbase = (w * 4 + mt) * 16 + quad * 4;
    const float4 bb = *(const float4*)&biasrc[mbase];
    #pragma unroll
    for (int et = 0; et < 4; ++et){
      const int e = et * 16 + l16;
      float4 o;
      o.x = gelu_exact(acc[mt][et][0] + bb.x);
      o.y = gelu_exact(acc[mt][et][1] + bb.y);
      o.z = gelu_exact(acc[mt][et][2] + bb.z);
      o.w = gelu_exact(acc[mt][et][3] + bb.w);
      *(float4*)&out[(size_t)(e0 + e) * 256 + mbase] = o;
    }
  }
}

// ---------------------------------------------------------------------------
extern "C" void kernel_launch(void* const* d_in, const int* in_sizes, int n_in,
                              void* d_out, int out_size, void* d_ws, size_t ws_size,
                              hipStream_t stream){
  const float* km   = (const float*)d_in[0];
  const int*   obsi = (const int*)d_in[1];
  const int*   omi  = (const int*)d_in[2];
  const int*   ai   = (const int*)d_in[3];
  const float* obs  = (const float*)d_in[4];
  const float* fe   = (const float*)d_in[5];
  const float* W1   = (const float*)d_in[6];
  const float* b1   = (const float*)d_in[7];
  const float* W2   = (const float*)d_in[8];
  const float* b2   = (const float*)d_in[9];
  const float* rrW  = (const float*)d_in[10];
  const float* rrb  = (const float*)d_in[11];
  const float* rcW  = (const float*)d_in[12];
  const float* rcb  = (const float*)d_in[13];
  float* out = (float*)d_out;

  char* ws = (char*)d_ws;
  float* Gm  = (float*)ws;                     // 16384 B
  bf16* W1s  = (bf16*)(ws + 16384);            // 32768 B
  bf16* W2s  = (bf16*)(ws + 49152);            // 32768 B
  bf16* RRs  = (bf16*)(ws + 81920);            // 32768 B
  bf16* RCs  = (bf16*)(ws + 114688);           // 131072 B  (total 245760 B)

  compute_g<<<dim3(64), dim3(64), 0, stream>>>(fe, Gm);
  swizzle_w<<<dim3(32),  dim3(64), 0, stream>>>(W1,  W1s, 64,  256);
  swizzle_w<<<dim3(32),  dim3(64), 0, stream>>>(W2,  W2s, 256, 64);
  swizzle_w<<<dim3(32),  dim3(64), 0, stream>>>(rrW, RRs, 64,  256);
  swizzle_w<<<dim3(128), dim3(64), 0, stream>>>(rcW, RCs, 256, 256);
  fused_attr_net<<<dim3(E_TOT / TE), dim3(256), 0, stream>>>(
      km, obsi, omi, ai, obs, b1, b2, rrb, rcb, Gm, W1s, W2s, RRs, RCs, out);
}

// Round 2
// 715.602 us; speedup vs baseline: 1.1775x; 1.0451x over previous
//
#include <hip/hip_runtime.h>
#include <hip/hip_bf16.h>

typedef __bf16 bf16;
typedef float f32x4 __attribute__((ext_vector_type(4)));
typedef bf16 bf16x8 __attribute__((ext_vector_type(8)));
typedef bf16 bf16x4 __attribute__((ext_vector_type(4)));

#define E_TOT 400000
#define TE 64          // edges per block
#define SROW 264       // LDS activation row stride (bf16 elems), 256+8 pad

// ---------------------------------------------------------------------------
// exact GELU (final layer only): A&S 7.1.26 erf, |err|<=1.5e-7.
// 1/x via hardware v_rcp (1 ulp) instead of IEEE div sequence.
// ---------------------------------------------------------------------------
__device__ __forceinline__ float gelu_exact(float x){
  float z = fabsf(x) * 0.70710678118654752f;
  float t = __builtin_amdgcn_rcpf(__builtin_fmaf(0.3275911f, z, 1.0f));
  float p = __builtin_fmaf(1.061405429f, t, -1.453152027f);
  p = __builtin_fmaf(p, t, 1.421413741f);
  p = __builtin_fmaf(p, t, -0.284496736f);
  p = __builtin_fmaf(p, t, 0.254829592f);
  p = p * t;
  float ex = __expf(-z * z);
  float er = __builtin_fmaf(-p, ex, 1.0f);
  er = copysignf(er, x);
  return 0.5f * x * (1.0f + er);
}

// ---------------------------------------------------------------------------
// fast GELU (hidden layers): tanh form, x*sigmoid(1.5957691*(x+0.044715x^3)).
// Max dev vs exact gelu ~5e-4 globally, <1e-6 for |x|<0.5; hidden activations
// are bf16-quantized (rel eps 4e-3) so this is below existing noise.
// 6 regular VALU + 1 v_exp + 1 v_rcp.
// ---------------------------------------------------------------------------
__device__ __forceinline__ float gelu_fast(float x){
  float x2 = x * x;
  float y  = x * __builtin_fmaf(0.07135482f, x2, 1.5957691216f);
  float e  = __expf(y);                               // v_mul + v_exp
  float r  = __builtin_amdgcn_rcpf(e + 1.0f);         // sigmoid(y) = 1-r... r = 1/(1+e^y)
  return __builtin_fmaf(-x, r, x);                    // x*(1 - 1/(1+e^y)) = x*sigmoid(y)
}

// ---------------------------------------------------------------------------
// G = feature_emb @ feature_emb.T  (64x64, fp32 in / fp32 out)
// ---------------------------------------------------------------------------
__global__ void compute_g(const float* __restrict__ fe, float* __restrict__ Gm){
  const int a = blockIdx.x, f = threadIdx.x;
  const float4* ra = (const float4*)(fe + a * 256);
  const float4* rf = (const float4*)(fe + f * 256);
  float s = 0.f;
  for (int h = 0; h < 64; ++h){
    float4 x = ra[h];
    float4 y = rf[h];
    s += x.x * y.x + x.y * y.y + x.z * y.z + x.w * y.w;
  }
  Gm[a * 64 + f] = s;
}

// ---------------------------------------------------------------------------
// Pre-swizzle fp32 weight W [Kd][Md] into bf16 MFMA A-operand fragments.
// ---------------------------------------------------------------------------
__global__ void swizzle_w(const float* __restrict__ src, bf16* __restrict__ dst,
                          int Kd, int Md){
  const int t = blockIdx.x;
  const int L = threadIdx.x;            // 64
  const int Mtiles = Md >> 4;
  const int kt = t / Mtiles, mtg = t % Mtiles;
  const int k0 = kt * 32 + (L >> 4) * 8;
  const int m  = mtg * 16 + (L & 15);
  bf16x8 v;
  #pragma unroll
  for (int j = 0; j < 8; ++j) v[j] = (bf16)src[(k0 + j) * Md + m];
  *(bf16x8*)&dst[((size_t)t * 64 + L) * 8] = v;
}

// ---------------------------------------------------------------------------
// Per-wave GEMM with bias-initialized accumulators:
//   acc[mt][et] starts at binit[mt] (broadcast over the 4 acc rows handled by
//   per-lane quad offset encoded in binit), so epilogues skip the bias add.
// ---------------------------------------------------------------------------
template<int KT, int MT, int MTOT>
__device__ __forceinline__ void mfma_gemm(const bf16* __restrict__ Wz,
                                          const bf16* __restrict__ src,
                                          int w, int lane,
                                          const float4 (&binit)[MT],
                                          f32x4 (&acc)[MT][4])
{
  const int l16 = lane & 15, quad = lane >> 4;
  #pragma unroll
  for (int mt = 0; mt < MT; ++mt)
    #pragma unroll
    for (int et = 0; et < 4; ++et)
      acc[mt][et] = f32x4{binit[mt].x, binit[mt].y, binit[mt].z, binit[mt].w};
  #pragma unroll
  for (int kt = 0; kt < KT; ++kt){
    bf16x8 b[4];
    #pragma unroll
    for (int et = 0; et < 4; ++et)
      b[et] = *(const bf16x8*)&src[(et * 16 + l16) * SROW + kt * 32 + quad * 8];
    #pragma unroll
    for (int mt = 0; mt < MT; ++mt){
      const bf16x8 a = *(const bf16x8*)&Wz[(size_t)((kt * MTOT + (w * MT + mt)) * 64 + lane) * 8];
      #pragma unroll
      for (int et = 0; et < 4; ++et)
        acc[mt][et] = __builtin_amdgcn_mfma_f32_16x16x32_bf16(a, b[et], acc[mt][et], 0, 0, 0);
    }
  }
}

// ---------------------------------------------------------------------------
// Fused main kernel: 64 edges per block, 256 threads (4 waves).
// Single LDS activation buffer (RAW resolved in registers), 4 blocks/CU.
// ---------------------------------------------------------------------------
__global__ __launch_bounds__(256, 4) void fused_attr_net(
    const float* __restrict__ km,        // [100000,64]
    const int*   __restrict__ obs_idx,   // [E]
    const int*   __restrict__ omi_idx,   // [E]
    const int*   __restrict__ ai_idx,    // [E]
    const float* __restrict__ obs_embs,  // [100000,256]
    const float* __restrict__ b1g, const float* __restrict__ b2g,
    const float* __restrict__ rrbg, const float* __restrict__ rcbg,
    const float* __restrict__ Gm,        // [64,64] fp32
    const bf16* __restrict__ W1s, const bf16* __restrict__ W2s,
    const bf16* __restrict__ RRs, const bf16* __restrict__ RCs,
    float* __restrict__ out)
{
  __shared__ __align__(16) bf16 S_[TE * SROW];   // 33792 B, single buffer
  __shared__ int ai_s[TE];
  __shared__ int oi_s[TE];
  __shared__ __align__(16) float bias1[256];
  __shared__ __align__(16) float bias2[64];
  __shared__ __align__(16) float biasrr[256];
  __shared__ __align__(16) float biasrc[256];

  const int tid  = threadIdx.x;
  const int e0   = blockIdx.x * TE;
  const int lane = tid & 63;
  const int w    = tid >> 6;
  const int l16  = lane & 15;
  const int quad = lane >> 4;

  bias1[tid]  = b1g[tid];
  biasrr[tid] = rrbg[tid];
  biasrc[tid] = rcbg[tid];
  if (tid < TE){
    bias2[tid] = b2g[tid];
    ai_s[tid]  = ai_idx[e0 + tid];
    oi_s[tid]  = obs_idx[e0 + tid];
  }

  // ---- stage 0: SM = softmax(known_mask[omi] * (1-eye)[ai]) -> S_[e][0..63]
  {
    const int e = tid >> 2, part = tid & 3;      // 4 threads x 16 feats per edge
    const int omi = omi_idx[e0 + e];
    const int ai  = ai_idx[e0 + e];
    const float4* kr = (const float4*)(km + omi * 64 + part * 16);
    float s[16]; float cnt = 0.f;
    #pragma unroll
    for (int q = 0; q < 4; ++q){
      const float4 v4 = kr[q];
      const float vv[4] = {v4.x, v4.y, v4.z, v4.w};
      #pragma unroll
      for (int j = 0; j < 4; ++j){
        const int f = part * 16 + q * 4 + j;
        const float v = (f == ai) ? 0.f : vv[j];
        s[q * 4 + j] = v; cnt += v;
      }
    }
    cnt += __shfl_xor(cnt, 1);
    cnt += __shfl_xor(cnt, 2);
    // s in {0,1}: sum(exp) = cnt*e + (64-cnt)
    const float denom = __builtin_fmaf(cnt, 1.7182818284590452f, 64.0f);
    const float p0 = __builtin_amdgcn_rcpf(denom);
    const float d10 = 1.7182818284590452f * p0;   // p1 - p0
    bf16x8 o0, o1;
    #pragma unroll
    for (int j = 0; j < 8; ++j) o0[j] = (bf16)__builtin_fmaf(s[j],     d10, p0);
    #pragma unroll
    for (int j = 0; j < 8; ++j) o1[j] = (bf16)__builtin_fmaf(s[8 + j], d10, p0);
    *(bf16x8*)&S_[e * SROW + part * 16]     = o0;
    *(bf16x8*)&S_[e * SROW + part * 16 + 8] = o1;
  }
  __syncthreads();

  f32x4 acc[4][4];
  float4 binit4[4];
  float4 binit1[1];

  // ---- GEMM1: H1 = gelu(SM @ W1 + b1)  [64e x 256] -> S_
  #pragma unroll
  for (int mt = 0; mt < 4; ++mt)
    binit4[mt] = *(const float4*)&bias1[(w * 4 + mt) * 16 + quad * 4];
  mfma_gemm<2, 4, 16>(W1s, S_, w, lane, binit4, acc);
  __syncthreads();                      // all waves done reading SM
  #pragma unroll
  for (int mt = 0; mt < 4; ++mt){
    const int mbase = (w * 4 + mt) * 16 + quad * 4;
    #pragma unroll
    for (int et = 0; et < 4; ++et){
      const int e = et * 16 + l16;
      bf16x4 o;
      o[0] = (bf16)gelu_fast(acc[mt][et][0]);
      o[1] = (bf16)gelu_fast(acc[mt][et][1]);
      o[2] = (bf16)gelu_fast(acc[mt][et][2]);
      o[3] = (bf16)gelu_fast(acc[mt][et][3]);
      *(bf16x4*)&S_[e * SROW + mbase] = o;
    }
  }
  __syncthreads();

  // ---- GEMM2: R = gelu(H1 @ W2 + b2) * G[ai]  [64e x 64] -> S_
  {
    f32x4 acc2[1][4];
    binit1[0] = *(const float4*)&bias2[w * 16 + quad * 4];
    mfma_gemm<8, 1, 4>(W2s, S_, w, lane, binit1, acc2);
    __syncthreads();                    // all waves done reading H1
    const int mbase = w * 16 + quad * 4;
    #pragma unroll
    for (int et = 0; et < 4; ++et){
      const int e = et * 16 + l16;
      const float4 g = *(const float4*)&Gm[ai_s[e] * 64 + mbase];
      bf16x4 o;
      o[0] = (bf16)(gelu_fast(acc2[0][et][0]) * g.x);
      o[1] = (bf16)(gelu_fast(acc2[0][et][1]) * g.y);
      o[2] = (bf16)(gelu_fast(acc2[0][et][2]) * g.z);
      o[3] = (bf16)(gelu_fast(acc2[0][et][3]) * g.w);
      *(bf16x4*)&S_[e * SROW + mbase] = o;
    }
  }
  __syncthreads();

  // ---- GEMM3: P = gelu(R @ rrW + rrb) * obs_embs[oi]  [64e x 256] -> S_
  #pragma unroll
  for (int mt = 0; mt < 4; ++mt)
    binit4[mt] = *(const float4*)&biasrr[(w * 4 + mt) * 16 + quad * 4];
  mfma_gemm<2, 4, 16>(RRs, S_, w, lane, binit4, acc);
  __syncthreads();                      // all waves done reading R
  #pragma unroll
  for (int mt = 0; mt < 4; ++mt){
    const int mbase = (w * 4 + mt) * 16 + quad * 4;
    #pragma unroll
    for (int et = 0; et < 4; ++et){
      const int e = et * 16 + l16;
      const float4 oh = *(const float4*)&obs_embs[(size_t)oi_s[e] * 256 + mbase];
      bf16x4 o;
      o[0] = (bf16)(gelu_fast(acc[mt][et][0]) * oh.x);
      o[1] = (bf16)(gelu_fast(acc[mt][et][1]) * oh.y);
      o[2] = (bf16)(gelu_fast(acc[mt][et][2]) * oh.z);
      o[3] = (bf16)(gelu_fast(acc[mt][et][3]) * oh.w);
      *(bf16x4*)&S_[e * SROW + mbase] = o;
    }
  }
  __syncthreads();

  // ---- GEMM4: OUT = gelu(P @ rcW + rcb) -> direct fp32 global store
  //      final layer: exact erf (fp32-visible, no bf16 masking downstream)
  #pragma unroll
  for (int mt = 0; mt < 4; ++mt)
    binit4[mt] = *(const float4*)&biasrc[(w * 4 + mt) * 16 + quad * 4];
  mfma_gemm<8, 4, 16>(RCs, S_, w, lane, binit4, acc);
  #pragma unroll
  for (int mt = 0; mt < 4; ++mt){
    const int mbase = (w * 4 + mt) * 16 + quad * 4;
    #pragma unroll
    for (int et = 0; et < 4; ++et){
      const int e = et * 16 + l16;
      float4 o;
      o.x = gelu_exact(acc[mt][et][0]);
      o.y = gelu_exact(acc[mt][et][1]);
      o.z = gelu_exact(acc[mt][et][2]);
      o.w = gelu_exact(acc[mt][et][3]);
      *(float4*)&out[(size_t)(e0 + e) * 256 + mbase] = o;
    }
  }
}

// ---------------------------------------------------------------------------
extern "C" void kernel_launch(void* const* d_in, const int* in_sizes, int n_in,
                              void* d_out, int out_size, void* d_ws, size_t ws_size,
                              hipStream_t stream){
  const float* km   = (const float*)d_in[0];
  const int*   obsi = (const int*)d_in[1];
  const int*   omi  = (const int*)d_in[2];
  const int*   ai   = (const int*)d_in[3];
  const float* obs  = (const float*)d_in[4];
  const float* fe   = (const float*)d_in[5];
  const float* W1   = (const float*)d_in[6];
  const float* b1   = (const float*)d_in[7];
  const float* W2   = (const float*)d_in[8];
  const float* b2   = (const float*)d_in[9];
  const float* rrW  = (const float*)d_in[10];
  const float* rrb  = (const float*)d_in[11];
  const float* rcW  = (const float*)d_in[12];
  const float* rcb  = (const float*)d_in[13];
  float* out = (float*)d_out;

  char* ws = (char*)d_ws;
  float* Gm  = (float*)ws;                     // 16384 B
  bf16* W1s  = (bf16*)(ws + 16384);            // 32768 B
  bf16* W2s  = (bf16*)(ws + 49152);            // 32768 B
  bf16* RRs  = (bf16*)(ws + 81920);            // 32768 B
  bf16* RCs  = (bf16*)(ws + 114688);           // 131072 B  (total 245760 B)

  compute_g<<<dim3(64), dim3(64), 0, stream>>>(fe, Gm);
  swizzle_w<<<dim3(32),  dim3(64), 0, stream>>>(W1,  W1s, 64,  256);
  swizzle_w<<<dim3(32),  dim3(64), 0, stream>>>(W2,  W2s, 256, 64);
  swizzle_w<<<dim3(32),  dim3(64), 0, stream>>>(rrW, RRs, 64,  256);
  swizzle_w<<<dim3(128), dim3(64), 0, stream>>>(rcW, RCs, 256, 256);
  fused_attr_net<<<dim3(E_TOT / TE), dim3(256), 0, stream>>>(
      km, obsi, omi, ai, obs, b1, b2, rrb, rcb, Gm, W1s, W2s, RRs, RCs, out);
}